// Round 1
// baseline (11145.947 us; speedup 1.0000x reference)
//
#include <hip/hip_runtime.h>
#include <math.h>

#define EMBED 2048
#define DFF   8192
#define TOK   4096   // B*N rows
#define HEADS 16
#define HD    128
#define SEQ   2048
#define BQ    4      // query rows per attention workgroup

// ---------------------------------------------------------------------------
// fp32 tiled GEMM: Y[M,N] = X[M,K] @ W[K,N] + bias[N]  (+ resid)  (+ GELU)
// 64x64 tile, BK=16, 256 threads, 4x4 micro-tile per thread.
// ---------------------------------------------------------------------------
template<bool GELU>
__global__ __launch_bounds__(256)
void gemm_kernel(const float* __restrict__ X, const float* __restrict__ W,
                 const float* __restrict__ bias, const float* __restrict__ resid,
                 float* __restrict__ Y, int M, int N, int K)
{
    __shared__ float Xs[16][68];   // [k][m], stride 68 keeps float4 16B-aligned
    __shared__ float Ws[16][68];   // [k][n]
    const int t  = threadIdx.x;
    const int tx = t & 15, ty = t >> 4;
    const int bm = blockIdx.y * 64, bn = blockIdx.x * 64;

    float acc[4][4] = {};
    for (int k0 = 0; k0 < K; k0 += 16) {
        {   // X tile: 64 rows x 16 k -> transposed into Xs[k][m]
            const int row = t >> 2, col = (t & 3) * 4;
            const float4 xv = *(const float4*)&X[(size_t)(bm + row) * K + k0 + col];
            Xs[col + 0][row] = xv.x; Xs[col + 1][row] = xv.y;
            Xs[col + 2][row] = xv.z; Xs[col + 3][row] = xv.w;
        }
        {   // W tile: 16 k x 64 n -> Ws[k][n]
            const int row = t >> 4, col = (t & 15) * 4;
            const float4 wv = *(const float4*)&W[(size_t)(k0 + row) * N + bn + col];
            *(float4*)&Ws[row][col] = wv;
        }
        __syncthreads();
#pragma unroll
        for (int kk = 0; kk < 16; ++kk) {
            const float4 a = *(const float4*)&Xs[kk][ty * 4];
            const float4 b = *(const float4*)&Ws[kk][tx * 4];
            const float av[4] = {a.x, a.y, a.z, a.w};
            const float bv[4] = {b.x, b.y, b.z, b.w};
#pragma unroll
            for (int i = 0; i < 4; ++i)
#pragma unroll
                for (int j = 0; j < 4; ++j)
                    acc[i][j] = fmaf(av[i], bv[j], acc[i][j]);
        }
        __syncthreads();
    }
#pragma unroll
    for (int i = 0; i < 4; ++i) {
        const int m = bm + ty * 4 + i;
#pragma unroll
        for (int j = 0; j < 4; ++j) {
            const int n = bn + tx * 4 + j;
            float y = acc[i][j] + bias[n];
            if (resid) y += resid[(size_t)m * N + n];
            if (GELU)  y = 0.5f * y * (1.0f + erff(y * 0.70710678118654752f));
            Y[(size_t)m * N + n] = y;
        }
    }
}

// ---------------------------------------------------------------------------
// Attention: one workgroup = one (b, h, 4-query block).
// Q/K/V/O layout: [B*N rows][EMBED] with head h at columns h*HD .. h*HD+127.
// ---------------------------------------------------------------------------
__global__ __launch_bounds__(256)
void attn_kernel(const float* __restrict__ Q, const float* __restrict__ Km,
                 const float* __restrict__ V, float* __restrict__ O)
{
    const int qb = blockIdx.x & 511;        // SEQ/BQ = 512 query blocks
    const int bh = blockIdx.x >> 9;         // 0..31
    const int b  = bh >> 4, h = bh & 15;
    const int t  = threadIdx.x;

    __shared__ float Qs[BQ][HD];            // 2 KB
    __shared__ float Sc[BQ][SEQ];           // 32 KB
    __shared__ float red[256];              // 1 KB

    const size_t base = (size_t)b * SEQ * EMBED + (size_t)h * HD;
    const int n0 = qb * BQ;

    for (int idx = t; idx < BQ * HD; idx += 256) {
        const int qi = idx >> 7, d = idx & 127;
        Qs[qi][d] = Q[base + (size_t)(n0 + qi) * EMBED + d];
    }
    __syncthreads();

    // ---- phase 1: scores (each thread owns 8 key rows) ----
    for (int it = 0; it < SEQ / 256; ++it) {
        const int j = t + it * 256;
        const float4* kr = (const float4*)&Km[base + (size_t)j * EMBED];
        float s0 = 0.f, s1 = 0.f, s2 = 0.f, s3 = 0.f;
#pragma unroll 8
        for (int d4 = 0; d4 < HD / 4; ++d4) {
            const float4 kv = kr[d4];
            const float4 q0 = *(const float4*)&Qs[0][d4 * 4];
            const float4 q1 = *(const float4*)&Qs[1][d4 * 4];
            const float4 q2 = *(const float4*)&Qs[2][d4 * 4];
            const float4 q3 = *(const float4*)&Qs[3][d4 * 4];
            s0 += kv.x * q0.x + kv.y * q0.y + kv.z * q0.z + kv.w * q0.w;
            s1 += kv.x * q1.x + kv.y * q1.y + kv.z * q1.z + kv.w * q1.w;
            s2 += kv.x * q2.x + kv.y * q2.y + kv.z * q2.z + kv.w * q2.w;
            s3 += kv.x * q3.x + kv.y * q3.y + kv.z * q3.z + kv.w * q3.w;
        }
        const float scale = 0.088388347648318447f;  // 1/sqrt(128)
        Sc[0][j] = s0 * scale;
        Sc[1][j] = s1 * scale;
        Sc[2][j] = s2 * scale;
        Sc[3][j] = s3 * scale;
    }
    __syncthreads();

    // ---- softmax per query row ----
    for (int qi = 0; qi < BQ; ++qi) {
        float m = -1e30f;
        for (int j = t; j < SEQ; j += 256) m = fmaxf(m, Sc[qi][j]);
        red[t] = m; __syncthreads();
        for (int s = 128; s > 0; s >>= 1) {
            if (t < s) red[t] = fmaxf(red[t], red[t + s]);
            __syncthreads();
        }
        m = red[0]; __syncthreads();
        float sum = 0.f;
        for (int j = t; j < SEQ; j += 256) {
            const float e = __expf(Sc[qi][j] - m);
            Sc[qi][j] = e;
            sum += e;
        }
        red[t] = sum; __syncthreads();
        for (int s = 128; s > 0; s >>= 1) {
            if (t < s) red[t] += red[t + s];
            __syncthreads();
        }
        const float inv = 1.0f / red[0];
        __syncthreads();
        for (int j = t; j < SEQ; j += 256) Sc[qi][j] *= inv;
        __syncthreads();
    }

    // ---- phase 2: O = P @ V (thread t owns dim d = t&127, 2 query rows) ----
    const int d = t & 127, qg = t >> 7;
    float o0 = 0.f, o1 = 0.f;
#pragma unroll 4
    for (int j = 0; j < SEQ; ++j) {
        const float vv = V[base + (size_t)j * EMBED + d];
        o0 += Sc[qg * 2 + 0][j] * vv;
        o1 += Sc[qg * 2 + 1][j] * vv;
    }
    O[base + (size_t)(n0 + qg * 2 + 0) * EMBED + d] = o0;
    O[base + (size_t)(n0 + qg * 2 + 1) * EMBED + d] = o1;
}

// ---------------------------------------------------------------------------
// LayerNorm: one block per row of EMBED elements.
// ---------------------------------------------------------------------------
__global__ __launch_bounds__(256)
void ln_kernel(const float* __restrict__ X, const float* __restrict__ gamma,
               const float* __restrict__ beta, float* __restrict__ Y)
{
    const int row = blockIdx.x;
    const float* x = X + (size_t)row * EMBED;
    float* y = Y + (size_t)row * EMBED;
    __shared__ float r1[256], r2[256];
    const int t = threadIdx.x;
    float s = 0.f, s2 = 0.f;
    for (int j = t; j < EMBED; j += 256) {
        const float v = x[j];
        s += v; s2 += v * v;
    }
    r1[t] = s; r2[t] = s2; __syncthreads();
    for (int k = 128; k > 0; k >>= 1) {
        if (t < k) { r1[t] += r1[t + k]; r2[t] += r2[t + k]; }
        __syncthreads();
    }
    const float mu  = r1[0] * (1.0f / EMBED);
    const float var = r2[0] * (1.0f / EMBED) - mu * mu;
    const float rs  = rsqrtf(var + 1e-5f);
    for (int j = t; j < EMBED; j += 256)
        y[j] = (x[j] - mu) * rs * gamma[j] + beta[j];
}

// ---------------------------------------------------------------------------
extern "C" void kernel_launch(void* const* d_in, const int* in_sizes, int n_in,
                              void* d_out, int out_size, void* d_ws, size_t ws_size,
                              hipStream_t stream)
{
    const float* x   = (const float*)d_in[0];
    const float* Wq  = (const float*)d_in[1];
    const float* bq  = (const float*)d_in[2];
    const float* Wk  = (const float*)d_in[3];
    const float* bk  = (const float*)d_in[4];
    const float* Wv  = (const float*)d_in[5];
    const float* bv  = (const float*)d_in[6];
    const float* Wo  = (const float*)d_in[7];
    const float* bo  = (const float*)d_in[8];
    const float* g1  = (const float*)d_in[9];
    const float* b1  = (const float*)d_in[10];
    const float* g2v = (const float*)d_in[11];
    const float* b2v = (const float*)d_in[12];
    const float* W1  = (const float*)d_in[13];
    const float* bf1 = (const float*)d_in[14];
    const float* W2  = (const float*)d_in[15];
    const float* bf2 = (const float*)d_in[16];
    float* out = (float*)d_out;

    // workspace layout (floats); total 48M floats = 192 MiB
    const size_t ACT = (size_t)TOK * EMBED;       // 8M floats
    float* q    = (float*)d_ws;                   // [0,   8M)
    float* kbuf = q    + ACT;                     // [8M, 16M)
    float* vbuf = kbuf + ACT;                     // [16M,24M)
    float* ao   = vbuf + ACT;                     // [24M,32M)
    float* res1 = q;      // q dead after attention
    float* h    = kbuf;   // k dead after attention
    float* ff   = vbuf;   // spans [16M,48M); v/ao dead after Wo-proj
    float* res2 = q;      // res1 dead after LN1

    const dim3 blk(256);
    const dim3 gE(EMBED / 64, TOK / 64);          // (32,64)
    const dim3 gF(DFF / 64, TOK / 64);            // (128,64)

    // QKV projections
    gemm_kernel<false><<<gE, blk, 0, stream>>>(x, Wq, bq, nullptr, q,    TOK, EMBED, EMBED);
    gemm_kernel<false><<<gE, blk, 0, stream>>>(x, Wk, bk, nullptr, kbuf, TOK, EMBED, EMBED);
    gemm_kernel<false><<<gE, blk, 0, stream>>>(x, Wv, bv, nullptr, vbuf, TOK, EMBED, EMBED);

    // attention
    attn_kernel<<<dim3(2 * HEADS * (SEQ / BQ)), blk, 0, stream>>>(q, kbuf, vbuf, ao);

    // output projection + residual
    gemm_kernel<false><<<gE, blk, 0, stream>>>(ao, Wo, bo, x, res1, TOK, EMBED, EMBED);
    ln_kernel<<<dim3(TOK), blk, 0, stream>>>(res1, g1, b1, h);

    // FFN
    gemm_kernel<true ><<<gF, blk, 0, stream>>>(h,  W1, bf1, nullptr, ff,   TOK, DFF,   EMBED);
    gemm_kernel<false><<<gE, blk, 0, stream>>>(ff, W2, bf2, h,       res2, TOK, EMBED, DFF);
    ln_kernel<<<dim3(TOK), blk, 0, stream>>>(res2, g2v, b2v, out);
}

// Round 3
// 1013.800 us; speedup vs baseline: 10.9942x; 10.9942x over previous
//
#include <hip/hip_runtime.h>
#include <math.h>

#define EMBED 2048
#define DFF   8192
#define TOK   4096
#define SEQ   2048
#define HEADS 16
#define HD    128
#define LDQ   6144   // qkv row stride in elements (q|k|v concatenated)

typedef __attribute__((ext_vector_type(8))) short short8;
typedef __attribute__((ext_vector_type(4))) float f32x4;

__device__ __forceinline__ unsigned short f2bf(float f) {
    unsigned int u = __float_as_uint(f);
    return (unsigned short)((u + 0x7FFFu + ((u >> 16) & 1u)) >> 16);  // RNE
}
__device__ __forceinline__ float bf2f(unsigned short s) {
    return __uint_as_float(((unsigned int)s) << 16);
}

// async global->LDS, 16B per lane. LDS dest = wave-uniform base + lane*16.
__device__ __forceinline__ void async16(const void* g, void* l) {
    __builtin_amdgcn_global_load_lds((const __attribute__((address_space(1))) void*)g,
                                     (__attribute__((address_space(3))) void*)l, 16, 0, 0);
}

// ---------------------------------------------------------------------------
// bf16 MFMA GEMM: C[M,N](bf16) = A[M,K](bf16) @ Wt[N,K](bf16)^T + bias (+epi)
// 128x128 tile, BK=32, 256 thr = 4 waves (2x2 of 64x64), 16x16x32 MFMA.
// LDS slot-swizzle: chunk c of row r stored at slot c ^ ((r>>1)&3)  (16B slots)
// MODE: 0 plain, 1 +resid f32, 2 +GELU, 3 +resid bf16. Output always bf16.
// ---------------------------------------------------------------------------
template<int MODE>
__global__ __launch_bounds__(256, 2)
void gemm_bf16(const unsigned short* __restrict__ A, const unsigned short* __restrict__ B,
               const float* __restrict__ bias, const void* __restrict__ resid,
               unsigned short* __restrict__ C, int M, int N, int K, int lda)
{
    __shared__ unsigned short As[128*32];
    __shared__ unsigned short Bs[128*32];
    const int t = threadIdx.x;
    const int w = t >> 6, l = t & 63;
    const int quad = l >> 4, m16 = l & 15;
    const long bm = (long)blockIdx.y * 128, bn = (long)blockIdx.x * 128;
    const int wr = (w >> 1)*64, wc = (w & 1)*64;   // this wave's 64x64 quadrant

    f32x4 acc[4][4] = {};

    const int srow = w*16 + (l >> 2);   // staging row (+u*64)
    const int sslot = l & 3;

    for (int k0 = 0; k0 < K; k0 += 32) {
        __syncthreads();
#pragma unroll
        for (int u = 0; u < 2; ++u) {
            const int row = u*64 + srow;
            const int c = sslot ^ ((row >> 1) & 3);
            async16(A + (size_t)(bm + row)*lda + k0 + c*8, As + u*2048 + w*512);
            async16(B + (size_t)(bn + row)*K   + k0 + c*8, Bs + u*2048 + w*512);
        }
        __syncthreads();
        short8 af[4], bf[4];
#pragma unroll
        for (int s = 0; s < 4; ++s) {
            const int ra = wr + s*16 + m16;                 // FIX: + wave row offset
            const int sla = quad ^ ((ra >> 1) & 3);
            af[s] = *(const short8*)&As[ra*32 + sla*8];
            const int rb = wc + s*16 + m16;                 // FIX: + wave col offset
            const int slb = quad ^ ((rb >> 1) & 3);
            bf[s] = *(const short8*)&Bs[rb*32 + slb*8];
        }
#pragma unroll
        for (int ms = 0; ms < 4; ++ms)
#pragma unroll
            for (int ns = 0; ns < 4; ++ns)
                acc[ms][ns] = __builtin_amdgcn_mfma_f32_16x16x32_bf16(af[ms], bf[ns], acc[ms][ns], 0, 0, 0);
    }

    // epilogue: D row = quad*4+reg, col = lane&15  [verified m89/m91]
#pragma unroll
    for (int ns = 0; ns < 4; ++ns) {
        const long gc = bn + wc + ns*16 + m16;
        const float bcol = bias[gc];
#pragma unroll
        for (int ms = 0; ms < 4; ++ms) {
#pragma unroll
            for (int r = 0; r < 4; ++r) {
                const long gr = bm + wr + ms*16 + quad*4 + r;
                float v = acc[ms][ns][r] + bcol;
                if (MODE == 1) v += ((const float*)resid)[gr*N + gc];
                if (MODE == 3) v += bf2f(((const unsigned short*)resid)[gr*N + gc]);
                if (MODE == 2) v = 0.5f*v*(1.0f + erff(v*0.70710678118654752f));
                C[gr*N + gc] = f2bf(v);
            }
        }
    }
}

// ---------------------------------------------------------------------------
// Flash attention, bf16 MFMA. One block = (b, h, 64-row Q tile). 256 thr.
// qkv layout: [4096 rows][6144] bf16 = q|k|v, head h at cols h*128 (+0/2048/4096).
// O is written in-place over the Q columns (only this block reads them).
// ---------------------------------------------------------------------------
__global__ __launch_bounds__(256, 2)
void attn_flash(unsigned short* __restrict__ qkv)
{
    __shared__ unsigned short Qs[64*128];   // raw glds layout, 16B-slot swizzle (r>>1)&7
    __shared__ unsigned short Ks[64*128];
    __shared__ unsigned short Vt[128*72];   // V^T [d][j], col j ^ (((d>>5)&3)<<3)
    __shared__ unsigned short Ps[4*16*72];  // per-wave P scratch

    const int t = threadIdx.x;
    const int w = t >> 6, l = t & 63;
    const int quad = l >> 4, m16 = l & 15;

    const int qt = blockIdx.x & 31;
    const int bh = blockIdx.x >> 5;
    const int b = bh >> 4, h = bh & 15;

    const long rowq = (long)b*SEQ + qt*64;
    const int qc = h*HD;
    const int kc = EMBED + h*HD;
    const int vc = 2*EMBED + h*HD;

    // ---- stage Q once ----
    {
        const int rbase = w*4 + (l >> 4);
        const int slot = l & 15;
#pragma unroll
        for (int u = 0; u < 4; ++u) {
            const int row = u*16 + rbase;
            const int c = slot ^ ((row >> 1) & 7);
            async16(qkv + (rowq + row)*LDQ + qc + c*8, Qs + u*2048 + w*512);
        }
    }
    __syncthreads();

    // Q A-frags live in registers for the whole K loop
    short8 af[4];
#pragma unroll
    for (int ks = 0; ks < 4; ++ks) {
        const int row = w*16 + m16;
        const int sl = (4*ks + quad) ^ ((row >> 1) & 7);
        af[ks] = *(const short8*)&Qs[row*128 + sl*8];
    }

    f32x4 O[8] = {};
    float mrun[4] = {-1e30f,-1e30f,-1e30f,-1e30f};
    float lrun[4] = {0.f,0.f,0.f,0.f};
    unsigned short* Pw = Ps + w*16*72;

    for (int kt = 0; kt < SEQ/64; ++kt) {
        const long rowkv = (long)b*SEQ + kt*64;
        __syncthreads();
        // stage K (async, raw)
        {
            const int rbase = w*4 + (l >> 4);
            const int slot = l & 15;
#pragma unroll
            for (int u = 0; u < 4; ++u) {
                const int row = u*16 + rbase;
                const int c = slot ^ ((row >> 1) & 7);
                async16(qkv + (rowkv + row)*LDQ + kc + c*8, Ks + u*2048 + w*512);
            }
        }
        // stage V transposed (pack j-pairs -> b32 writes)
        {
            const int slot = t & 15;
#pragma unroll
            for (int u = 0; u < 2; ++u) {
                const int rp = u*16 + (t >> 4);
                const short8 va = *(const short8*)(qkv + (rowkv + 2*rp    )*LDQ + vc + slot*8);
                const short8 vb = *(const short8*)(qkv + (rowkv + 2*rp + 1)*LDQ + vc + slot*8);
#pragma unroll
                for (int i = 0; i < 8; ++i) {
                    const int d = slot*8 + i;
                    const int col = (2*rp) ^ (((d >> 5) & 3) << 3);
                    unsigned int pv = (unsigned int)(unsigned short)va[i] |
                                      ((unsigned int)(unsigned short)vb[i] << 16);
                    *(unsigned int*)&Vt[d*72 + col] = pv;
                }
            }
        }
        __syncthreads();

        // ---- S = Q K^T (16 q-rows per wave x 64 j) ----
        f32x4 S[4];
#pragma unroll
        for (int ns = 0; ns < 4; ++ns) {
            f32x4 a = {0.f,0.f,0.f,0.f};
            const int row = ns*16 + m16;
            const int swr = (row >> 1) & 7;
#pragma unroll
            for (int ks = 0; ks < 4; ++ks) {
                const int sl = (4*ks + quad) ^ swr;
                const short8 bf = *(const short8*)&Ks[row*128 + sl*8];
                a = __builtin_amdgcn_mfma_f32_16x16x32_bf16(af[ks], bf, a, 0, 0, 0);
            }
#pragma unroll
            for (int r = 0; r < 4; ++r) a[r] *= 0.08838834764831845f; // 1/sqrt(128)
            S[ns] = a;
        }

        // ---- online softmax (lane holds rows quad*4+r, cols m16) ----
        float al[4], rs[4];
#pragma unroll
        for (int r = 0; r < 4; ++r) {
            float tm = fmaxf(fmaxf(S[0][r], S[1][r]), fmaxf(S[2][r], S[3][r]));
            tm = fmaxf(tm, __shfl_xor(tm, 1));
            tm = fmaxf(tm, __shfl_xor(tm, 2));
            tm = fmaxf(tm, __shfl_xor(tm, 4));
            tm = fmaxf(tm, __shfl_xor(tm, 8));
            const float mn = fmaxf(mrun[r], tm);
            al[r] = __expf(mrun[r] - mn);
            mrun[r] = mn;
            rs[r] = 0.f;
        }
#pragma unroll
        for (int ns = 0; ns < 4; ++ns)
#pragma unroll
            for (int r = 0; r < 4; ++r) {
                const float p = __expf(S[ns][r] - mrun[r]);
                rs[r] += p;
                Pw[(quad*4 + r)*72 + ns*16 + m16] = f2bf(p);
            }
#pragma unroll
        for (int r = 0; r < 4; ++r) {
            rs[r] += __shfl_xor(rs[r], 1);
            rs[r] += __shfl_xor(rs[r], 2);
            rs[r] += __shfl_xor(rs[r], 4);
            rs[r] += __shfl_xor(rs[r], 8);
            lrun[r] = lrun[r]*al[r] + rs[r];
        }
#pragma unroll
        for (int i = 0; i < 8; ++i)
#pragma unroll
            for (int r = 0; r < 4; ++r) O[i][r] *= al[r];

        // ---- O += P V  (P via LDS: C-layout -> A-layout round trip) ----
#pragma unroll
        for (int ks2 = 0; ks2 < 2; ++ks2) {
            const short8 ap = *(const short8*)&Pw[m16*72 + ks2*32 + quad*8];
#pragma unroll
            for (int ds = 0; ds < 8; ++ds) {
                const int d = ds*16 + m16;
                const int jcol = (ks2*32 + quad*8) ^ (((d >> 5) & 3) << 3);
                const short8 bv = *(const short8*)&Vt[d*72 + jcol];
                O[ds] = __builtin_amdgcn_mfma_f32_16x16x32_bf16(ap, bv, O[ds], 0, 0, 0);
            }
        }
    }

    // ---- normalize + write O over the Q columns ----
    float inv[4];
#pragma unroll
    for (int r = 0; r < 4; ++r) inv[r] = 1.0f / lrun[r];
#pragma unroll
    for (int ds = 0; ds < 8; ++ds)
#pragma unroll
        for (int r = 0; r < 4; ++r) {
            const long row = rowq + w*16 + quad*4 + r;
            qkv[row*LDQ + qc + ds*16 + m16] = f2bf(O[ds][r] * inv[r]);
        }
}

// ---------------------------------------------------------------------------
// LayerNorm over bf16 rows. OUTF32=1 writes fp32 (final output), else bf16.
// ---------------------------------------------------------------------------
template<int OUTF32>
__global__ __launch_bounds__(256)
void ln_bf16(const unsigned short* __restrict__ X, const float* __restrict__ g,
             const float* __restrict__ be, void* __restrict__ Y)
{
    __shared__ float r1[256], r2[256];
    const int t = threadIdx.x;
    const long row = blockIdx.x;
    const unsigned short* x = X + row*EMBED;
    float v[8];
    const short8 xv = *(const short8*)(x + t*8);
    float s = 0.f, s2 = 0.f;
#pragma unroll
    for (int i = 0; i < 8; ++i) {
        v[i] = bf2f((unsigned short)xv[i]);
        s += v[i]; s2 += v[i]*v[i];
    }
    r1[t] = s; r2[t] = s2;
    __syncthreads();
    for (int k = 128; k > 0; k >>= 1) {
        if (t < k) { r1[t] += r1[t+k]; r2[t] += r2[t+k]; }
        __syncthreads();
    }
    const float mu = r1[0] * (1.0f/EMBED);
    const float var = r2[0] * (1.0f/EMBED) - mu*mu;
    const float rstd = rsqrtf(var + 1e-5f);
    if (OUTF32) {
        float* y = (float*)Y + row*EMBED + t*8;
#pragma unroll
        for (int i = 0; i < 8; ++i) y[i] = (v[i]-mu)*rstd*g[t*8+i] + be[t*8+i];
    } else {
        unsigned short* y = (unsigned short*)Y + row*EMBED;
        short8 o;
#pragma unroll
        for (int i = 0; i < 8; ++i) o[i] = (short)f2bf((v[i]-mu)*rstd*g[t*8+i] + be[t*8+i]);
        *(short8*)(y + t*8) = o;
    }
}

// ---------------------------------------------------------------------------
// fp32 W[K][N] -> bf16 Wt[N][K] (transpose + convert), 32x32 LDS tiles
// ---------------------------------------------------------------------------
__global__ __launch_bounds__(256)
void cvt_transpose(const float* __restrict__ W, unsigned short* __restrict__ Wt, int K, int N)
{
    __shared__ unsigned short T[32][33];
    const int t = threadIdx.x;
    const long n0 = (long)blockIdx.x*32, k0 = (long)blockIdx.y*32;
    {
        const int r = t >> 3, c = (t & 7)*4;
        const float4 vv = *(const float4*)&W[(k0 + r)*N + n0 + c];
        T[r][c+0] = f2bf(vv.x); T[r][c+1] = f2bf(vv.y);
        T[r][c+2] = f2bf(vv.z); T[r][c+3] = f2bf(vv.w);
    }
    __syncthreads();
    const int rn = t >> 3, kk = (t & 7)*4;
    unsigned int p0 = (unsigned int)T[kk+0][rn] | ((unsigned int)T[kk+1][rn] << 16);
    unsigned int p1 = (unsigned int)T[kk+2][rn] | ((unsigned int)T[kk+3][rn] << 16);
    unsigned int* dst = (unsigned int*)&Wt[(n0 + rn)*K + k0 + kk];
    dst[0] = p0; dst[1] = p1;
}

__global__ __launch_bounds__(256)
void cvt_f32_bf16(const float* __restrict__ X, unsigned short* __restrict__ Y, long n)
{
    const long i = ((long)blockIdx.x*256 + threadIdx.x)*8;
    if (i >= n) return;
    const float4 a = *(const float4*)&X[i];
    const float4 b = *(const float4*)&X[i+4];
    short8 o;
    o[0]=(short)f2bf(a.x); o[1]=(short)f2bf(a.y); o[2]=(short)f2bf(a.z); o[3]=(short)f2bf(a.w);
    o[4]=(short)f2bf(b.x); o[5]=(short)f2bf(b.y); o[6]=(short)f2bf(b.z); o[7]=(short)f2bf(b.w);
    *(short8*)&Y[i] = o;
}

__global__ __launch_bounds__(256)
void concat_bias(const float* __restrict__ bq, const float* __restrict__ bk,
                 const float* __restrict__ bv, float* __restrict__ out)
{
    const int i = blockIdx.x*256 + threadIdx.x;
    if (i < 2048) out[i] = bq[i];
    else if (i < 4096) out[i] = bk[i-2048];
    else if (i < 6144) out[i] = bv[i-4096];
}

// ---------------------------------------------------------------------------
extern "C" void kernel_launch(void* const* d_in, const int* in_sizes, int n_in,
                              void* d_out, int out_size, void* d_ws, size_t ws_size,
                              hipStream_t stream)
{
    const float* x   = (const float*)d_in[0];
    const float* Wq  = (const float*)d_in[1];
    const float* bq  = (const float*)d_in[2];
    const float* Wk  = (const float*)d_in[3];
    const float* bk  = (const float*)d_in[4];
    const float* Wv  = (const float*)d_in[5];
    const float* bv  = (const float*)d_in[6];
    const float* Wo  = (const float*)d_in[7];
    const float* bo  = (const float*)d_in[8];
    const float* g1  = (const float*)d_in[9];
    const float* b1  = (const float*)d_in[10];
    const float* g2v = (const float*)d_in[11];
    const float* b2v = (const float*)d_in[12];
    const float* W1  = (const float*)d_in[13];
    const float* bf1 = (const float*)d_in[14];
    const float* W2  = (const float*)d_in[15];
    const float* bf2 = (const float*)d_in[16];
    float* out = (float*)d_out;

    // ---- workspace arena (byte offsets; total 184,573,952 B < 192 MiB) ----
    char* ws = (char*)d_ws;
    unsigned short* Wqkvt = (unsigned short*)(ws + 0);          // 25.2 MB [dead after GEMM1]
    unsigned short* Wot   = (unsigned short*)(ws + 25165824);   //  8.4 MB
    unsigned short* W1t   = (unsigned short*)(ws + 33554432);   // 33.6 MB
    unsigned short* W2t   = (unsigned short*)(ws + 67108864);   // 33.6 MB
    float*          bqkv  = (float*)         (ws + 100663296);  // 24 KB
    char* arenaA = ws + 100687872;                              // 67.1 MB arena
    unsigned short* xb   = (unsigned short*)(arenaA);           // 16.8 MB [cvt_x, GEMM1]
    unsigned short* qkv  = (unsigned short*)(arenaA + 16777216);// 50.3 MB [GEMM1, GEMM2]
    unsigned short* res1 = (unsigned short*)(arenaA);           // reuse xb slot [GEMM2, LN1]
    unsigned short* ff   = (unsigned short*)(arenaA);           // full arena [GEMM3, GEMM4]
    unsigned short* hb   = (unsigned short*)(ws + 167796736);   // 16.8 MB [LN1, GEMM4]
    unsigned short* res2 = (unsigned short*)(ws + 0);           // reuse Wqkvt slot [GEMM4, LN2]

    const dim3 blk(256);

    // weights: fp32 -> bf16 transposed
    cvt_transpose<<<dim3(64,64),  blk, 0, stream>>>(Wq, Wqkvt,             2048, 2048);
    cvt_transpose<<<dim3(64,64),  blk, 0, stream>>>(Wk, Wqkvt + 2048*2048, 2048, 2048);
    cvt_transpose<<<dim3(64,64),  blk, 0, stream>>>(Wv, Wqkvt + 2*2048*2048, 2048, 2048);
    cvt_transpose<<<dim3(64,64),  blk, 0, stream>>>(Wo, Wot, 2048, 2048);
    cvt_transpose<<<dim3(256,64), blk, 0, stream>>>(W1, W1t, 2048, 8192);
    cvt_transpose<<<dim3(64,256), blk, 0, stream>>>(W2, W2t, 8192, 2048);
    concat_bias<<<dim3(24), blk, 0, stream>>>(bq, bk, bv, bqkv);
    cvt_f32_bf16<<<dim3(4096), blk, 0, stream>>>(x, xb, (long)TOK*EMBED);

    // fused QKV projection -> qkv[4096][6144]
    gemm_bf16<0><<<dim3(48,32), blk, 0, stream>>>(xb, Wqkvt, bqkv, nullptr, qkv, TOK, 6144, 2048, 2048);
    // flash attention (O overwrites q-columns in-place)
    attn_flash<<<dim3(1024), blk, 0, stream>>>(qkv);
    // output projection + residual(x, fp32)
    gemm_bf16<1><<<dim3(16,32), blk, 0, stream>>>(qkv, Wot, bo, x, res1, TOK, 2048, 2048, 6144);
    ln_bf16<0><<<dim3(4096), blk, 0, stream>>>(res1, g1, b1, hb);
    // FFN
    gemm_bf16<2><<<dim3(64,32), blk, 0, stream>>>(hb, W1t, bf1, nullptr, ff, TOK, 8192, 2048, 2048);
    gemm_bf16<3><<<dim3(16,32), blk, 0, stream>>>(ff, W2t, bf2, hb, res2, TOK, 2048, 8192, 8192);
    ln_bf16<1><<<dim3(4096), blk, 0, stream>>>(res2, g2v, b2v, out);
}